// Round 5
// baseline (199.636 us; speedup 1.0000x reference)
//
#include <hip/hip_runtime.h>
#include <cstdint>

#define FP8_MAX_F 448.0f

typedef float floatx4 __attribute__((ext_vector_type(4)));
typedef int   intx4   __attribute__((ext_vector_type(4)));
typedef int   intx8   __attribute__((ext_vector_type(8)));

static constexpr int Mdim = 2048;
static constexpr int Ndim = 4096;
static constexpr int Kdim = 4096;
static constexpr int BM = 128;
static constexpr int BN = 256;
static constexpr int BK = 128;   // fp8 bytes of K per staged tile
static constexpr int KT = Kdim / BK;  // 32 K-iterations

// amax: 8 float4 per thread, exact cover
static constexpr int A_XB = 1024;
static constexpr int A_WB = 2048;

__device__ __forceinline__ void async_load16(const void* g, void* l) {
  __builtin_amdgcn_global_load_lds((__attribute__((address_space(1))) void*)g,
                                   (__attribute__((address_space(3))) void*)l,
                                   16, 0, 0);
}

// ---------------------------------------------------------------------------
// Pass 1: per-block partial abs-max, both tensors in one dispatch.
// ---------------------------------------------------------------------------
__global__ void amax_partials(const float* __restrict__ x,
                              const float* __restrict__ w,
                              float* __restrict__ part) {
  const int b = blockIdx.x;
  const float4* p4;
  float* dst;
  int bid;
  if (b < A_XB) { p4 = (const float4*)x; dst = part;        bid = b; }
  else          { p4 = (const float4*)w; dst = part + A_XB; bid = b - A_XB; }
  const int tid = threadIdx.x;
  const int base = bid * 2048 + tid;
  float4 v[8];
#pragma unroll
  for (int u = 0; u < 8; u++) v[u] = p4[base + u * 256];
  float m = 0.f;
#pragma unroll
  for (int u = 0; u < 8; u++)
    m = fmaxf(m, fmaxf(fmaxf(fabsf(v[u].x), fabsf(v[u].y)),
                       fmaxf(fabsf(v[u].z), fabsf(v[u].w))));
#pragma unroll
  for (int off = 32; off > 0; off >>= 1)
    m = fmaxf(m, __shfl_down(m, off, 64));
  __shared__ float red[4];
  if ((tid & 63) == 0) red[tid >> 6] = m;
  __syncthreads();
  if (tid == 0)
    dst[bid] = fmaxf(fmaxf(red[0], red[1]), fmaxf(red[2], red[3]));
}

// ---------------------------------------------------------------------------
// Pass 2: reduce partials -> per-tensor amax, then quantize fp32 -> fp8
// e4m3fn (native OCP grid, RNE via v_cvt_pk_fp8_f32). Mirrors reference fp32
// arithmetic exactly: amax = max(|t|,1e-12); scale = 448/amax; clip; round.
// ---------------------------------------------------------------------------
__global__ void quant_both(const float* __restrict__ x,
                           const float* __restrict__ w,
                           const float* __restrict__ part,
                           unsigned int* __restrict__ qx,
                           unsigned int* __restrict__ qw,
                           float* __restrict__ scalars) {
  const int b = blockIdx.x;
  const float4* p4;
  const float* po;
  unsigned int* q;
  float* slot;
  int np, bid;
  if (b < A_XB) { p4 = (const float4*)x; po = part;        q = qx; np = A_XB; bid = b;        slot = scalars;     }
  else          { p4 = (const float4*)w; po = part + A_XB; q = qw; np = A_WB; bid = b - A_XB; slot = scalars + 1; }
  const int tid = threadIdx.x;

  float m = 0.f;
  for (int i = tid; i < np; i += 256) m = fmaxf(m, po[i]);
#pragma unroll
  for (int off = 32; off > 0; off >>= 1)
    m = fmaxf(m, __shfl_down(m, off, 64));
  __shared__ float red[4];
  __shared__ float amax_s;
  if ((tid & 63) == 0) red[tid >> 6] = m;
  __syncthreads();
  if (tid == 0) {
    float mm = fmaxf(fmaxf(fmaxf(red[0], red[1]), fmaxf(red[2], red[3])), 1e-12f);
    amax_s = mm;
    if (bid == 0) *slot = mm;
  }
  __syncthreads();
  const float scale = FP8_MAX_F / amax_s;

  const int base = bid * 2048 + tid;
#pragma unroll
  for (int u = 0; u < 8; u++) {
    float4 v = p4[base + u * 256];
    float a = fminf(fmaxf(v.x * scale, -FP8_MAX_F), FP8_MAX_F);
    float bb = fminf(fmaxf(v.y * scale, -FP8_MAX_F), FP8_MAX_F);
    float c = fminf(fmaxf(v.z * scale, -FP8_MAX_F), FP8_MAX_F);
    float d = fminf(fmaxf(v.w * scale, -FP8_MAX_F), FP8_MAX_F);
    unsigned int r = 0;
    r = __builtin_amdgcn_cvt_pk_fp8_f32(a, bb, r, false);
    r = __builtin_amdgcn_cvt_pk_fp8_f32(c, d, r, true);
    q[base + u * 256] = r;
  }
}

// ---------------------------------------------------------------------------
// FP8 GEMM (mfma_scale_f32_16x16x128_f8f6f4, unit e8m0 scales). R9 =
// faithful 8-phase-template port (T3+T4+T5), resubmitted unchanged after
// R8's infra failure (container failed twice; no kernel verdict). Audit
// found no hang-capable construct: barriers are wave-uniform, WAR discipline
// sound, raw s_barrier + asm waitcnt already ran on this harness in R6.
//
// Rationale: R4/R5/R7 all hit ~3400 cyc/K-tile at 3 different LDS-traffic
// levels -> not traffic-bound; the invariant wall is the per-K-step all-wave
// drain (2-phase structure ceiling, m233). Per-phase schedule:
//
//   per K-tile (BK=128), 4 phases; each phase =
//     { ds_read this phase's fragments (6/6/2/2 x b128);
//       issue 2 global_load_lds quanta for tile kt+1 (P0:A, P1:B01, P2:B23);
//       s_barrier;  s_waitcnt lgkmcnt(0); sched_barrier(0);   // rule 18
//       s_setprio(1); MFMA burst (2/4/4/6); s_setprio(0);
//       s_barrier; }
//   The ONLY vmcnt in the loop is at P3's end, waiting quanta issued 1..3
//   phases (~700-2000 cyc) earlier -> nothing young is drained; loads span
//   phases (T4). Distinct a0..a3 regs -> no WAR serialization.
//
// Geometry: BM=128 x BN=256, 512 thr, 8 waves 2Mx4N, wave = 64x64
// (acc[4][4]), LDS = 2x16K (A) + 2x32K (B) = 96 KiB, 1 block/CU, 256 blocks
// = chip-filling; same residency profile as the proven m201 template.
//
// LDS rows of 128B = 8 chunks of 16B, XOR-swizzled: logical chunk c of row
// r at physical chunk c ^ (r&7); staging pins LDS dst to tid*16 per 8KB
// quantum (64 rows) and pre-swizzles the global source column. Fragment
// layouts (HW-verified m89/m148 + 7 passing rounds): A: lane holds
// A[m=lane&15][k=(lane>>4)*32+j]; C/D: col=lane&15, row=(lane>>4)*4+reg.
// ---------------------------------------------------------------------------
__launch_bounds__(512, 2)
__global__ void gemm_fp8(const unsigned char* __restrict__ qx,
                         const unsigned char* __restrict__ qw,
                         const float* __restrict__ bias,
                         const float* __restrict__ scalars,
                         float* __restrict__ out) {
  __shared__ __align__(16) unsigned char As[2 * BM * BK];  // 2 x 16 KiB
  __shared__ __align__(16) unsigned char Bs[2 * BN * BK];  // 2 x 32 KiB

  const int tid = threadIdx.x;   // 0..511
  const int lane = tid & 63;
  const int wv = tid >> 6;       // 0..7
  const int wm = (wv & 1) * 64;  // wave M offset (2 rows of waves)
  const int wn = (wv >> 1) * 64; // wave N offset (4 cols of waves)

  // XCD-aware bijective swizzle over the 16(by) x 16(bx) block grid.
  const int bid = blockIdx.x;            // 0..255
  const int xcd = bid & 7;
  const int idx = bid >> 3;              // 0..31
  const int by = (xcd & 3) * 4 + (idx & 3);    // 0..15 (M)
  const int bx = (xcd >> 2) * 8 + (idx >> 2);  // 0..15 (N)
  const int bm0 = by * BM;
  const int bn0 = bx * BN;

  // Staging: 6 async16/thread per K-tile (A: 2 quanta of 64 rows, B: 4).
  const int srow = tid >> 3;                          // 0..63
  const int sc = ((tid & 7) ^ ((tid >> 3) & 7)) << 4; // swizzled source col
  const unsigned char* gA0 = qx + (size_t)(bm0 + srow) * Kdim + sc;
  const unsigned char* gB0 = qw + (size_t)(bn0 + srow) * Kdim + sc;
  const size_t rstep = (size_t)64 * Kdim;
  const int lslot = tid * 16;

  floatx4 acc[4][4];
#pragma unroll
  for (int i = 0; i < 4; i++)
#pragma unroll
    for (int j = 0; j < 4; j++) acc[i][j] = (floatx4){0.f, 0.f, 0.f, 0.f};

  // Fragment read constants
  const int frow = lane & 15;
  const int h = lane >> 4;                   // k-block 0..3 (32B each)
  const int fr7 = frow & 7;
  const int kc0 = ((2 * h) ^ fr7) << 4;
  const int kc1 = ((2 * h + 1) ^ fr7) << 4;

#define LDFRAG(dst, basePtr, row16)                                   \
  do {                                                                \
    const unsigned char* rp_ = (basePtr) + ((row16) + frow) * BK;     \
    intx4 lo_ = *(const intx4*)(rp_ + kc0);                           \
    intx4 hi_ = *(const intx4*)(rp_ + kc1);                           \
    dst = __builtin_shufflevector(lo_, hi_, 0, 1, 2, 3, 4, 5, 6, 7);  \
  } while (0)

#define MFMA(i, j, areg)                                              \
  acc[i][j] = __builtin_amdgcn_mfma_scale_f32_16x16x128_f8f6f4(       \
      areg, bf[j], acc[i][j], 0, 0, 0, 0x7F7F7F7F, 0, 0x7F7F7F7F)

  // Prologue: stage tile 0 into buffer 0 (6 quanta), full drain once.
  async_load16(gA0, As + lslot);
  async_load16(gA0 + rstep, As + 8192 + lslot);
#pragma unroll
  for (int r = 0; r < 4; r++)
    async_load16(gB0 + r * rstep, Bs + r * 8192 + lslot);
  __syncthreads();

  for (int kt = 0; kt < KT; ++kt) {
    const int abuf = (kt & 1) * 16384;
    const int bbuf = (kt & 1) * 32768;
    const bool have = (kt + 1 < KT);
    const int anb = ((kt + 1) & 1) * 16384;
    const int bnb = ((kt + 1) & 1) * 32768;
    const int k0 = (kt + 1) * BK;
    const unsigned char* Ab = As + abuf;
    const unsigned char* Bb = Bs + bbuf;

    intx8 bf[4], a0, a1, a2, a3;

    // ---- Phase 0: reads bf0,bf1,a0 ; stage A quanta ; MFMA (0,0)(0,1)
    LDFRAG(bf[0], Bb, wn + 0);
    LDFRAG(bf[1], Bb, wn + 16);
    LDFRAG(a0, Ab, wm + 0);
    if (have) {
      async_load16(gA0 + k0, As + anb + lslot);
      async_load16(gA0 + k0 + rstep, As + anb + 8192 + lslot);
    }
    __builtin_amdgcn_s_barrier();
    asm volatile("s_waitcnt lgkmcnt(0)" ::: "memory");
    __builtin_amdgcn_sched_barrier(0);
    __builtin_amdgcn_s_setprio(1);
    MFMA(0, 0, a0); MFMA(0, 1, a0);
    __builtin_amdgcn_s_setprio(0);
    __builtin_amdgcn_s_barrier();

    // ---- Phase 1: reads bf2,bf3,a1 ; stage B q0,q1 ; MFMA (0,2)(0,3)(1,0)(1,1)
    LDFRAG(bf[2], Bb, wn + 32);
    LDFRAG(bf[3], Bb, wn + 48);
    LDFRAG(a1, Ab, wm + 16);
    if (have) {
      async_load16(gB0 + k0, Bs + bnb + lslot);
      async_load16(gB0 + k0 + rstep, Bs + bnb + 8192 + lslot);
    }
    __builtin_amdgcn_s_barrier();
    asm volatile("s_waitcnt lgkmcnt(0)" ::: "memory");
    __builtin_amdgcn_sched_barrier(0);
    __builtin_amdgcn_s_setprio(1);
    MFMA(0, 2, a0); MFMA(0, 3, a0); MFMA(1, 0, a1); MFMA(1, 1, a1);
    __builtin_amdgcn_s_setprio(0);
    __builtin_amdgcn_s_barrier();

    // ---- Phase 2: reads a2 ; stage B q2,q3 ; MFMA (1,2)(1,3)(2,0)(2,1)
    LDFRAG(a2, Ab, wm + 32);
    if (have) {
      async_load16(gB0 + k0 + 2 * rstep, Bs + bnb + 16384 + lslot);
      async_load16(gB0 + k0 + 3 * rstep, Bs + bnb + 24576 + lslot);
    }
    __builtin_amdgcn_s_barrier();
    asm volatile("s_waitcnt lgkmcnt(0)" ::: "memory");
    __builtin_amdgcn_sched_barrier(0);
    __builtin_amdgcn_s_setprio(1);
    MFMA(1, 2, a1); MFMA(1, 3, a1); MFMA(2, 0, a2); MFMA(2, 1, a2);
    __builtin_amdgcn_s_setprio(0);
    __builtin_amdgcn_s_barrier();

    // ---- Phase 3: reads a3 ; MFMA (2,2)(2,3)(3,0..3) ; vmcnt on old quanta
    LDFRAG(a3, Ab, wm + 48);
    __builtin_amdgcn_s_barrier();
    asm volatile("s_waitcnt lgkmcnt(0)" ::: "memory");
    __builtin_amdgcn_sched_barrier(0);
    __builtin_amdgcn_s_setprio(1);
    MFMA(2, 2, a2); MFMA(2, 3, a2);
    MFMA(3, 0, a3); MFMA(3, 1, a3); MFMA(3, 2, a3); MFMA(3, 3, a3);
    __builtin_amdgcn_s_setprio(0);
    // Tile kt+1's 6 quanta were issued 1..3 phases ago — this wait is
    // near-free but guarantees residency before the buffer swap.
    asm volatile("s_waitcnt vmcnt(0)" ::: "memory");
    __builtin_amdgcn_s_barrier();
  }

  // Dequant scale, mirroring reference fp32 arithmetic exactly.
  float ax = fmaxf(scalars[0], 1e-12f);
  float aw = fmaxf(scalars[1], 1e-12f);
  float cs = (1.0f / (FP8_MAX_F / ax)) * (1.0f / (FP8_MAX_F / aw));

  const int crow = bm0 + wm + (lane >> 4) * 4;
  const int ccol = bn0 + wn + (lane & 15);
#pragma unroll
  for (int j = 0; j < 4; j++) {
    float bv = bias[ccol + j * 16];
#pragma unroll
    for (int i = 0; i < 4; i++) {
#pragma unroll
      for (int r = 0; r < 4; r++) {
        out[(size_t)(crow + i * 16 + r) * Ndim + (ccol + j * 16)] =
            acc[i][j][r] * cs + bv;
      }
    }
  }
#undef LDFRAG
#undef MFMA
}

extern "C" void kernel_launch(void* const* d_in, const int* in_sizes, int n_in,
                              void* d_out, int out_size, void* d_ws, size_t ws_size,
                              hipStream_t stream) {
  const float* x = (const float*)d_in[0];     // [M,K] fp32
  const float* w = (const float*)d_in[1];     // [N,K] fp32
  const float* bias = (const float*)d_in[2];  // [N] fp32
  float* out = (float*)d_out;                 // [M,N] fp32

  float* part = (float*)d_ws;
  float* scalars = part + 4096;
  unsigned char* qx = (unsigned char*)d_ws + 32768;
  unsigned char* qw = qx + (size_t)Mdim * Kdim;

  amax_partials<<<A_XB + A_WB, 256, 0, stream>>>(x, w, part);
  quant_both<<<A_XB + A_WB, 256, 0, stream>>>(x, w, part,
                                              (unsigned int*)qx, (unsigned int*)qw,
                                              scalars);
  gemm_fp8<<<256, 512, 0, stream>>>(qx, qw, bias, scalars, out);
}

// Round 6
// 196.665 us; speedup vs baseline: 1.0151x; 1.0151x over previous
//
#include <hip/hip_runtime.h>
#include <cstdint>

#define FP8_MAX_F 448.0f

typedef float floatx4 __attribute__((ext_vector_type(4)));
typedef int   intx4   __attribute__((ext_vector_type(4)));
typedef int   intx8   __attribute__((ext_vector_type(8)));

static constexpr int Mdim = 2048;
static constexpr int Ndim = 4096;
static constexpr int Kdim = 4096;
static constexpr int BM = 128;
static constexpr int BN = 128;
static constexpr int BK = 128;   // fp8 bytes of K per staged tile
static constexpr int KT = Kdim / BK;  // 32 K-iterations

// passes: 8 float4 per thread, exact cover
static constexpr int A_XB = 1024;  // 2048*4096/4 / (256*8)
static constexpr int A_WB = 2048;  // 4096*4096/4 / (256*8)

__device__ __forceinline__ void async_load16(const void* g, void* l) {
  __builtin_amdgcn_global_load_lds((__attribute__((address_space(1))) void*)g,
                                   (__attribute__((address_space(3))) void*)l,
                                   16, 0, 0);
}

// ---------------------------------------------------------------------------
// Pass 1: per-tensor abs-max in ONE pass. Per-block reduce, then a single
// device-scope atomicMax on the float bit-pattern (values >= 0, so uint
// compare == float compare). Eliminates the partials buffer, pass-2's
// reduce preamble, and its two __syncthreads. scalars[] zero-init'd by an
// 8-byte hipMemsetAsync (bits of +0.0f).
// ---------------------------------------------------------------------------
__global__ void amax_scalars(const float* __restrict__ x,
                             const float* __restrict__ w,
                             unsigned int* __restrict__ scalars) {
  const int b = blockIdx.x;
  const float4* p4;
  unsigned int* slot;
  int bid;
  if (b < A_XB) { p4 = (const float4*)x; slot = scalars;     bid = b; }
  else          { p4 = (const float4*)w; slot = scalars + 1; bid = b - A_XB; }
  const int tid = threadIdx.x;
  const int base = bid * 2048 + tid;
  float4 v[8];
#pragma unroll
  for (int u = 0; u < 8; u++) v[u] = p4[base + u * 256];
  float m = 0.f;
#pragma unroll
  for (int u = 0; u < 8; u++)
    m = fmaxf(m, fmaxf(fmaxf(fabsf(v[u].x), fabsf(v[u].y)),
                       fmaxf(fabsf(v[u].z), fabsf(v[u].w))));
#pragma unroll
  for (int off = 32; off > 0; off >>= 1)
    m = fmaxf(m, __shfl_down(m, off, 64));
  __shared__ float red[4];
  if ((tid & 63) == 0) red[tid >> 6] = m;
  __syncthreads();
  if (tid == 0) {
    float mm = fmaxf(fmaxf(red[0], red[1]), fmaxf(red[2], red[3]));
    atomicMax(slot, __float_as_uint(mm));  // one atomic per block
  }
}

// ---------------------------------------------------------------------------
// Pass 2: quantize fp32 -> fp8 e4m3fn (native OCP grid, RNE via
// v_cvt_pk_fp8_f32 — same grid as jnp float8_e4m3fn). Reads the scalar amax
// directly (uniform s_load), no block reduce, no LDS, no syncthreads.
// Mirrors reference fp32 arithmetic exactly: amax = max(|t|,1e-12);
// scale = 448/amax; clip to +-448; round.
// ---------------------------------------------------------------------------
__global__ void quant_both(const float* __restrict__ x,
                           const float* __restrict__ w,
                           const unsigned int* __restrict__ scalars,
                           unsigned int* __restrict__ qx,
                           unsigned int* __restrict__ qw) {
  const int b = blockIdx.x;
  const float4* p4;
  unsigned int* q;
  const unsigned int* sl;
  int bid;
  if (b < A_XB) { p4 = (const float4*)x; q = qx; bid = b;        sl = scalars;     }
  else          { p4 = (const float4*)w; q = qw; bid = b - A_XB; sl = scalars + 1; }
  const int tid = threadIdx.x;

  const float amax = fmaxf(__uint_as_float(*sl), 1e-12f);
  const float scale = FP8_MAX_F / amax;

  const int base = bid * 2048 + tid;
#pragma unroll
  for (int u = 0; u < 8; u++) {
    float4 v = p4[base + u * 256];
    float a = fminf(fmaxf(v.x * scale, -FP8_MAX_F), FP8_MAX_F);
    float bb = fminf(fmaxf(v.y * scale, -FP8_MAX_F), FP8_MAX_F);
    float c = fminf(fmaxf(v.z * scale, -FP8_MAX_F), FP8_MAX_F);
    float d = fminf(fmaxf(v.w * scale, -FP8_MAX_F), FP8_MAX_F);
    unsigned int r = 0;
    r = __builtin_amdgcn_cvt_pk_fp8_f32(a, bb, r, false);
    r = __builtin_amdgcn_cvt_pk_fp8_f32(c, d, r, true);
    q[base + u * 256] = r;
  }
}

// ---------------------------------------------------------------------------
// FP8 GEMM — EXACT round-0 kernel (best measured: 43.4 us, the only config
// that beat 44.8). R5..R9 post-mortems: 64x64 wave-tiles, XCD swizzles, and
// every explicit schedule (counted vmcnt, 4-phase, 8-phase) were neutral or
// regressed; the compiler-scheduled single-barrier double-buffered loop at
// 2 blocks/CU (cross-block drain hiding, m114 mechanism) is the proven
// optimum of the explored space. Restored verbatim.
//
// MX rate (mfma_scale_f32_16x16x128_f8f6f4, unit e8m0 scales = numerically
// plain fp8 dot + fp32 acc). Per K-iter: [barrier] [issue async loads for
// tile k+1 into buf (k+1)&1] [compute tile k from buf k&1]. 512 threads =
// 8 waves (2x4), each wave a 64x32 C-block (4x2 MFMA tiles); 16 waves/CU.
//
// LDS rows of 128B = 8 chunks of 16B, XOR-swizzled: logical chunk c of row r
// at physical chunk c ^ (r&7). Staging (LDS dst pinned to tid*16): thread t
// covers row t>>3 (+64 on 2nd load), phys chunk t&7 -> fetches global chunk
// (t&7)^((t>>3)&7) (lane constant). Read-side term: frow&7.
// Fragment layouts (HW-verified m89/m148): A: lane holds
// A[m=lane&15][k=(lane>>4)*32 + j], j=0..31; C/D: col=lane&15,
// row=(lane>>4)*4+reg_idx.
// ---------------------------------------------------------------------------
__launch_bounds__(512, 4)
__global__ void gemm_fp8(const unsigned char* __restrict__ qx,
                         const unsigned char* __restrict__ qw,
                         const float* __restrict__ bias,
                         const float* __restrict__ scalars,
                         float* __restrict__ out) {
  __shared__ __align__(16) unsigned char As[2 * BM * BK];  // 2 x 16 KiB
  __shared__ __align__(16) unsigned char Bs[2 * BN * BK];  // 2 x 16 KiB

  const int tid = threadIdx.x;   // 0..511
  const int lane = tid & 63;
  const int wv = tid >> 6;       // 0..7
  const int wm = (wv & 1) * 64;  // wave M offset (2 rows of waves)
  const int wn = (wv >> 1) * 32; // wave N offset (4 cols of waves)
  const int bm0 = blockIdx.y * BM;
  const int bn0 = blockIdx.x * BN;

  // Staging source map: 4 async16 per thread per tile-pair (A lo/hi, B lo/hi)
  const int srow = tid >> 3;                          // 0..63
  const int sc = ((tid & 7) ^ ((tid >> 3) & 7)) << 4; // swizzled source col
  const unsigned char* gA0 = qx + (size_t)(bm0 + srow) * Kdim + sc;
  const unsigned char* gB0 = qw + (size_t)(bn0 + srow) * Kdim + sc;
  const size_t rstep = (size_t)64 * Kdim;
  const int lslot = tid * 16;

  floatx4 acc[4][2];
#pragma unroll
  for (int i = 0; i < 4; i++)
#pragma unroll
    for (int j = 0; j < 2; j++) acc[i][j] = (floatx4){0.f, 0.f, 0.f, 0.f};

  // Fragment read constants
  const int frow = lane & 15;
  const int h = lane >> 4;                   // k-block 0..3 (32B each)
  const int fr7 = frow & 7;
  const int kc0 = ((2 * h) ^ fr7) << 4;      // phys offset of logical chunk 2h
  const int kc1 = ((2 * h + 1) ^ fr7) << 4;  // phys offset of chunk 2h+1

  // Prologue: stage tile 0 into buffer 0
  async_load16(gA0, As + lslot);
  async_load16(gA0 + rstep, As + 8192 + lslot);
  async_load16(gB0, Bs + lslot);
  async_load16(gB0 + rstep, Bs + 8192 + lslot);

  for (int kt = 0; kt < KT; ++kt) {
    __syncthreads();  // drains loads issued LAST iter (a full compute ago)
    const int buf = (kt & 1) * 16384;
    if (kt + 1 < KT) {
      const int nbuf = ((kt + 1) & 1) * 16384;
      const int k0 = (kt + 1) * BK;
      async_load16(gA0 + k0, As + nbuf + lslot);
      async_load16(gA0 + k0 + rstep, As + nbuf + 8192 + lslot);
      async_load16(gB0 + k0, Bs + nbuf + lslot);
      async_load16(gB0 + k0 + rstep, Bs + nbuf + 8192 + lslot);
    }

    intx8 af[4], bf[2];
#pragma unroll
    for (int t = 0; t < 4; t++) {
      const unsigned char* ra = As + buf + (wm + t * 16 + frow) * BK;
      intx4 lo = *(const intx4*)(ra + kc0);
      intx4 hi = *(const intx4*)(ra + kc1);
      af[t] = __builtin_shufflevector(lo, hi, 0, 1, 2, 3, 4, 5, 6, 7);
    }
#pragma unroll
    for (int u = 0; u < 2; u++) {
      const unsigned char* rb = Bs + buf + (wn + u * 16 + frow) * BK;
      intx4 lo = *(const intx4*)(rb + kc0);
      intx4 hi = *(const intx4*)(rb + kc1);
      bf[u] = __builtin_shufflevector(lo, hi, 0, 1, 2, 3, 4, 5, 6, 7);
    }
#pragma unroll
    for (int i = 0; i < 4; i++)
#pragma unroll
      for (int j = 0; j < 2; j++)
        acc[i][j] = __builtin_amdgcn_mfma_scale_f32_16x16x128_f8f6f4(
            af[i], bf[j], acc[i][j], 0 /*A=fp8*/, 0 /*B=fp8*/,
            0, 0x7F7F7F7F, 0, 0x7F7F7F7F);  // unit scales (e8m0 127 = 2^0)
  }

  // Dequant scale, mirroring reference fp32 arithmetic exactly.
  float ax = fmaxf(scalars[0], 1e-12f);
  float aw = fmaxf(scalars[1], 1e-12f);
  float cs = (1.0f / (FP8_MAX_F / ax)) * (1.0f / (FP8_MAX_F / aw));

  const int crow = bm0 + wm + (lane >> 4) * 4;
  const int ccol = bn0 + wn + (lane & 15);
#pragma unroll
  for (int j = 0; j < 2; j++) {
    float bv = bias[ccol + j * 16];
#pragma unroll
    for (int i = 0; i < 4; i++) {
#pragma unroll
      for (int r = 0; r < 4; r++) {
        out[(size_t)(crow + i * 16 + r) * Ndim + (ccol + j * 16)] =
            acc[i][j][r] * cs + bv;
      }
    }
  }
}

extern "C" void kernel_launch(void* const* d_in, const int* in_sizes, int n_in,
                              void* d_out, int out_size, void* d_ws, size_t ws_size,
                              hipStream_t stream) {
  const float* x = (const float*)d_in[0];     // [M,K] fp32
  const float* w = (const float*)d_in[1];     // [N,K] fp32
  const float* bias = (const float*)d_in[2];  // [N] fp32
  float* out = (float*)d_out;                 // [M,N] fp32

  // Workspace: scalars (2 x u32 float-bits) | pad to 32 KiB | qx | qw
  unsigned int* scalars = (unsigned int*)d_ws;
  unsigned char* qx = (unsigned char*)d_ws + 32768;
  unsigned char* qw = qx + (size_t)Mdim * Kdim;

  hipMemsetAsync(d_ws, 0, 8, stream);  // scalars = bits of +0.0f
  amax_scalars<<<A_XB + A_WB, 256, 0, stream>>>(x, w, scalars);
  quant_both<<<A_XB + A_WB, 256, 0, stream>>>(x, w, scalars,
                                              (unsigned int*)qx, (unsigned int*)qw);
  dim3 grid(Ndim / BN, Mdim / BM);  // 32 x 16 = 512 blocks, 512 threads
  gemm_fp8<<<grid, 512, 0, stream>>>(qx, qw, bias, (const float*)scalars, out);
}

// Round 9
// 184.299 us; speedup vs baseline: 1.0832x; 1.0671x over previous
//
#include <hip/hip_runtime.h>
#include <cstdint>

#define FP8_MAX_F 448.0f

typedef float floatx4 __attribute__((ext_vector_type(4)));
typedef int   intx4   __attribute__((ext_vector_type(4)));
typedef int   intx8   __attribute__((ext_vector_type(8)));

static constexpr int Mdim = 2048;
static constexpr int Ndim = 4096;
static constexpr int Kdim = 4096;
static constexpr int BM = 128;
static constexpr int BN = 128;
static constexpr int BK = 128;   // fp8 bytes of K per staged tile
static constexpr int KT = Kdim / BK;  // 32 K-iterations

// Pass geometry: 2048 blocks x 256 thr (G11 shape), exact cover:
// x = 2,097,152 float4 = 4/thread; w = 4,194,304 float4 = 8/thread.
static constexpr int QGRID = 2048;
static constexpr size_t NTHR = (size_t)QGRID * 256;  // 524288

__device__ __forceinline__ void async_load16(const void* g, void* l) {
  __builtin_amdgcn_global_load_lds((__attribute__((address_space(1))) void*)g,
                                   (__attribute__((address_space(3))) void*)l,
                                   16, 0, 0);
}

__device__ __forceinline__ float amax4(float m, float4 v) {
  return fmaxf(m, fmaxf(fmaxf(fabsf(v.x), fabsf(v.y)),
                        fmaxf(fabsf(v.z), fabsf(v.w))));
}

__device__ __forceinline__ unsigned int quant4(float4 v, float scale) {
  float a = fminf(fmaxf(v.x * scale, -FP8_MAX_F), FP8_MAX_F);
  float b = fminf(fmaxf(v.y * scale, -FP8_MAX_F), FP8_MAX_F);
  float c = fminf(fmaxf(v.z * scale, -FP8_MAX_F), FP8_MAX_F);
  float d = fminf(fmaxf(v.w * scale, -FP8_MAX_F), FP8_MAX_F);
  unsigned int r = 0;
  r = __builtin_amdgcn_cvt_pk_fp8_f32(a, b, r, false);
  r = __builtin_amdgcn_cvt_pk_fp8_f32(c, d, r, true);
  return r;
}

// ---------------------------------------------------------------------------
// Pass 1: streaming abs-max of BOTH tensors, per-block partials (no atomics,
// no init). 2048 blocks x 256 thr, 12 float4/thread, fully coalesced.
// R11 post-mortem: cooperative launch is incompatible with the harness's
// graph capture (silent non-launch -> poisoned outputs); device atomics to
// 2 hot addresses + an init memset cost +15us (R10). Partials it is.
// ---------------------------------------------------------------------------
__global__ __launch_bounds__(256)
void amax_partials(const float* __restrict__ x, const float* __restrict__ w,
                   float* __restrict__ partx, float* __restrict__ partw) {
  const int tid = threadIdx.x;
  const int bid = blockIdx.x;
  const size_t g = (size_t)bid * 256 + tid;
  const float4* x4 = (const float4*)x;
  const float4* w4 = (const float4*)w;

  float4 vx[4], vw[8];
#pragma unroll
  for (int t = 0; t < 4; t++) vx[t] = x4[g + (size_t)t * NTHR];
#pragma unroll
  for (int t = 0; t < 8; t++) vw[t] = w4[g + (size_t)t * NTHR];

  float mx = 0.f, mw = 0.f;
#pragma unroll
  for (int t = 0; t < 4; t++) mx = amax4(mx, vx[t]);
#pragma unroll
  for (int t = 0; t < 8; t++) mw = amax4(mw, vw[t]);
#pragma unroll
  for (int off = 32; off > 0; off >>= 1) {
    mx = fmaxf(mx, __shfl_down(mx, off, 64));
    mw = fmaxf(mw, __shfl_down(mw, off, 64));
  }
  __shared__ float rx[4], rw[4];
  if ((tid & 63) == 0) { rx[tid >> 6] = mx; rw[tid >> 6] = mw; }
  __syncthreads();
  if (tid == 0) {
    partx[bid] = fmaxf(fmaxf(rx[0], rx[1]), fmaxf(rx[2], rx[3]));
    partw[bid] = fmaxf(fmaxf(rw[0], rw[1]), fmaxf(rw[2], rw[3]));
  }
}

// ---------------------------------------------------------------------------
// Pass 2: every block redundantly reduces the 2048-entry partials (16 KB,
// L2/L3-hot, 8 loads/thread/tensor), then quantizes fp32 -> fp8 e4m3fn
// (native OCP grid, RNE via v_cvt_pk_fp8_f32 — the same grid as jnp
// float8_e4m3fn). Re-read of x,w is L3-warm (96 MB < 256 MB L3). Block 0
// publishes the two amax scalars for the gemm epilogue. Arithmetic chain
// mirrors the reference exactly: amax=max(|t|,1e-12); scale=448/amax;
// clip +-448; round.
// ---------------------------------------------------------------------------
__global__ __launch_bounds__(256)
void quant_both(const float* __restrict__ x, const float* __restrict__ w,
                const float* __restrict__ partx, const float* __restrict__ partw,
                unsigned int* __restrict__ qx, unsigned int* __restrict__ qw,
                float* __restrict__ scalars) {
  const int tid = threadIdx.x;
  const int bid = blockIdx.x;
  const size_t g = (size_t)bid * 256 + tid;
  const float4* x4 = (const float4*)x;
  const float4* w4 = (const float4*)w;

  float ax = 0.f, aw = 0.f;
#pragma unroll
  for (int i = 0; i < QGRID / 256; i++) {
    ax = fmaxf(ax, partx[tid + i * 256]);
    aw = fmaxf(aw, partw[tid + i * 256]);
  }
#pragma unroll
  for (int off = 32; off > 0; off >>= 1) {
    ax = fmaxf(ax, __shfl_down(ax, off, 64));
    aw = fmaxf(aw, __shfl_down(aw, off, 64));
  }
  __shared__ float rx[4], rw[4];
  __shared__ float sxs, sws;
  if ((tid & 63) == 0) { rx[tid >> 6] = ax; rw[tid >> 6] = aw; }
  __syncthreads();
  if (tid == 0) {
    float fax = fmaxf(fmaxf(fmaxf(rx[0], rx[1]), fmaxf(rx[2], rx[3])), 1e-12f);
    float faw = fmaxf(fmaxf(fmaxf(rw[0], rw[1]), fmaxf(rw[2], rw[3])), 1e-12f);
    sxs = FP8_MAX_F / fax;
    sws = FP8_MAX_F / faw;
    if (bid == 0) { scalars[0] = fax; scalars[1] = faw; }
  }
  __syncthreads();
  const float sx = sxs, sw = sws;

#pragma unroll
  for (int t = 0; t < 4; t++)
    qx[g + (size_t)t * NTHR] = quant4(x4[g + (size_t)t * NTHR], sx);
#pragma unroll
  for (int t = 0; t < 8; t++)
    qw[g + (size_t)t * NTHR] = quant4(w4[g + (size_t)t * NTHR], sw);
}

// ---------------------------------------------------------------------------
// FP8 GEMM — EXACT round-0 kernel (best measured: 43.4-45.2 us across three
// independent benches). R5..R9: 64x64 wave-tiles, XCD swizzles, and every
// explicit schedule (counted vmcnt, 4-phase, 8-phase) were neutral or
// regressed; the compiler-scheduled single-barrier double-buffered loop at
// 2 blocks/CU (cross-block drain hiding, m114 mechanism) is the proven
// optimum of the explored space. Untouched.
//
// MX rate (mfma_scale_f32_16x16x128_f8f6f4, unit e8m0 scales = numerically
// plain fp8 dot + fp32 acc). Per K-iter: [barrier] [issue async loads for
// tile k+1 into buf (k+1)&1] [compute tile k from buf k&1]. 512 threads =
// 8 waves (2x4), each wave a 64x32 C-block (4x2 MFMA tiles); 16 waves/CU.
//
// LDS rows of 128B = 8 chunks of 16B, XOR-swizzled: logical chunk c of row r
// at physical chunk c ^ (r&7). Staging (LDS dst pinned to tid*16): thread t
// covers row t>>3 (+64 on 2nd load), phys chunk t&7 -> fetches global chunk
// (t&7)^((t>>3)&7) (lane constant). Read-side term: frow&7.
// Fragment layouts (HW-verified m89/m148): A: lane holds
// A[m=lane&15][k=(lane>>4)*32 + j], j=0..31; C/D: col=lane&15,
// row=(lane>>4)*4+reg_idx.
// ---------------------------------------------------------------------------
__launch_bounds__(512, 4)
__global__ void gemm_fp8(const unsigned char* __restrict__ qx,
                         const unsigned char* __restrict__ qw,
                         const float* __restrict__ bias,
                         const float* __restrict__ scalars,
                         float* __restrict__ out) {
  __shared__ __align__(16) unsigned char As[2 * BM * BK];  // 2 x 16 KiB
  __shared__ __align__(16) unsigned char Bs[2 * BN * BK];  // 2 x 16 KiB

  const int tid = threadIdx.x;   // 0..511
  const int lane = tid & 63;
  const int wv = tid >> 6;       // 0..7
  const int wm = (wv & 1) * 64;  // wave M offset (2 rows of waves)
  const int wn = (wv >> 1) * 32; // wave N offset (4 cols of waves)
  const int bm0 = blockIdx.y * BM;
  const int bn0 = blockIdx.x * BN;

  // Staging source map: 4 async16 per thread per tile-pair (A lo/hi, B lo/hi)
  const int srow = tid >> 3;                          // 0..63
  const int sc = ((tid & 7) ^ ((tid >> 3) & 7)) << 4; // swizzled source col
  const unsigned char* gA0 = qx + (size_t)(bm0 + srow) * Kdim + sc;
  const unsigned char* gB0 = qw + (size_t)(bn0 + srow) * Kdim + sc;
  const size_t rstep = (size_t)64 * Kdim;
  const int lslot = tid * 16;

  floatx4 acc[4][2];
#pragma unroll
  for (int i = 0; i < 4; i++)
#pragma unroll
    for (int j = 0; j < 2; j++) acc[i][j] = (floatx4){0.f, 0.f, 0.f, 0.f};

  // Fragment read constants
  const int frow = lane & 15;
  const int h = lane >> 4;                   // k-block 0..3 (32B each)
  const int fr7 = frow & 7;
  const int kc0 = ((2 * h) ^ fr7) << 4;      // phys offset of logical chunk 2h
  const int kc1 = ((2 * h + 1) ^ fr7) << 4;  // phys offset of chunk 2h+1

  // Prologue: stage tile 0 into buffer 0
  async_load16(gA0, As + lslot);
  async_load16(gA0 + rstep, As + 8192 + lslot);
  async_load16(gB0, Bs + lslot);
  async_load16(gB0 + rstep, Bs + 8192 + lslot);

  for (int kt = 0; kt < KT; ++kt) {
    __syncthreads();  // drains loads issued LAST iter (a full compute ago)
    const int buf = (kt & 1) * 16384;
    if (kt + 1 < KT) {
      const int nbuf = ((kt + 1) & 1) * 16384;
      const int k0 = (kt + 1) * BK;
      async_load16(gA0 + k0, As + nbuf + lslot);
      async_load16(gA0 + k0 + rstep, As + nbuf + 8192 + lslot);
      async_load16(gB0 + k0, Bs + nbuf + lslot);
      async_load16(gB0 + k0 + rstep, Bs + nbuf + 8192 + lslot);
    }

    intx8 af[4], bf[2];
#pragma unroll
    for (int t = 0; t < 4; t++) {
      const unsigned char* ra = As + buf + (wm + t * 16 + frow) * BK;
      intx4 lo = *(const intx4*)(ra + kc0);
      intx4 hi = *(const intx4*)(ra + kc1);
      af[t] = __builtin_shufflevector(lo, hi, 0, 1, 2, 3, 4, 5, 6, 7);
    }
#pragma unroll
    for (int u = 0; u < 2; u++) {
      const unsigned char* rb = Bs + buf + (wn + u * 16 + frow) * BK;
      intx4 lo = *(const intx4*)(rb + kc0);
      intx4 hi = *(const intx4*)(rb + kc1);
      bf[u] = __builtin_shufflevector(lo, hi, 0, 1, 2, 3, 4, 5, 6, 7);
    }
#pragma unroll
    for (int i = 0; i < 4; i++)
#pragma unroll
      for (int j = 0; j < 2; j++)
        acc[i][j] = __builtin_amdgcn_mfma_scale_f32_16x16x128_f8f6f4(
            af[i], bf[j], acc[i][j], 0 /*A=fp8*/, 0 /*B=fp8*/,
            0, 0x7F7F7F7F, 0, 0x7F7F7F7F);  // unit scales (e8m0 127 = 2^0)
  }

  // Dequant scale, mirroring reference fp32 arithmetic exactly.
  float ax = fmaxf(scalars[0], 1e-12f);
  float aw = fmaxf(scalars[1], 1e-12f);
  float cs = (1.0f / (FP8_MAX_F / ax)) * (1.0f / (FP8_MAX_F / aw));

  const int crow = bm0 + wm + (lane >> 4) * 4;
  const int ccol = bn0 + wn + (lane & 15);
#pragma unroll
  for (int j = 0; j < 2; j++) {
    float bv = bias[ccol + j * 16];
#pragma unroll
    for (int i = 0; i < 4; i++) {
#pragma unroll
      for (int r = 0; r < 4; r++) {
        out[(size_t)(crow + i * 16 + r) * Ndim + (ccol + j * 16)] =
            acc[i][j][r] * cs + bv;
      }
    }
  }
}

extern "C" void kernel_launch(void* const* d_in, const int* in_sizes, int n_in,
                              void* d_out, int out_size, void* d_ws, size_t ws_size,
                              hipStream_t stream) {
  const float* x = (const float*)d_in[0];     // [M,K] fp32
  const float* w = (const float*)d_in[1];     // [N,K] fp32
  const float* bias = (const float*)d_in[2];  // [N] fp32
  float* out = (float*)d_out;                 // [M,N] fp32

  // Workspace: partx[2048] | partw[2048] | scalars[2] | pad to 32 KiB | qx | qw
  float* partx = (float*)d_ws;
  float* partw = partx + QGRID;
  float* scalars = partw + QGRID;
  unsigned char* qx = (unsigned char*)d_ws + 32768;
  unsigned char* qw = qx + (size_t)Mdim * Kdim;

  amax_partials<<<QGRID, 256, 0, stream>>>(x, w, partx, partw);
  quant_both<<<QGRID, 256, 0, stream>>>(x, w, partx, partw,
                                        (unsigned int*)qx, (unsigned int*)qw,
                                        scalars);
  dim3 grid(Ndim / BN, Mdim / BM);  // 32 x 16 = 512 blocks, 512 threads
  gemm_fp8<<<grid, 512, 0, stream>>>(qx, qw, bias, scalars, out);
}